// Round 3
// baseline (744.054 us; speedup 1.0000x reference)
//
#include <hip/hip_runtime.h>
#include <math.h>

#define HW 784      // 28*28
#define TSTEPS 30

struct GaussW { float w[7]; };

// Exact-rounded f32 ops (never fused/contracted) to bitwise-match numpy f32.
__device__ __forceinline__ float fadd(float a, float b) { return __fadd_rn(a, b); }
__device__ __forceinline__ float fmul(float a, float b) { return __fmul_rn(a, b); }
__device__ __forceinline__ float fsub(float a, float b) { return __fsub_rn(a, b); }

__device__ __forceinline__ int refl(int i, int n) {
    // numpy 'symmetric' pad mapping for i in [-3, n+2]
    if (i < 0) return -i - 1;
    if (i >= n) return 2 * n - 1 - i;
    return i;
}

// Computes d[p] = |gauss4d(x)[b,p] - x[b,p]| into dout (LDS, 784 floats).
// Bitwise-mirrors reference order: axis0 (batch), axis1 (size-1 channel),
// axis2 (H), axis3 (W); sequential w[0]*s + w[1]*s + ... with rounded f32 ops.
__device__ void dog_sample(const float* __restrict__ x, int b, int nbatch,
                           const GaussW gw, float* g, float* t, float* xl,
                           float* dout, int tid) {
    for (int p = tid; p < HW; p += 256) {
        // axis 0: batch blur with symmetric padding
        float acc = fmul(gw.w[0], x[(size_t)refl(b - 3, nbatch) * HW + p]);
        #pragma unroll
        for (int k = 1; k < 7; ++k)
            acc = fadd(acc, fmul(gw.w[k], x[(size_t)refl(b - 3 + k, nbatch) * HW + p]));
        // axis 1: channel dim has size 1 -> every symmetric-pad slice equals acc
        float h = fmul(gw.w[0], acc);
        #pragma unroll
        for (int k = 1; k < 7; ++k)
            h = fadd(h, fmul(gw.w[k], acc));
        g[p] = h;
        xl[p] = x[(size_t)b * HW + p];
    }
    __syncthreads();
    for (int p = tid; p < HW; p += 256) {
        int i = p / 28, j = p - (p / 28) * 28;
        float acc = fmul(gw.w[0], g[refl(i - 3, 28) * 28 + j]);
        #pragma unroll
        for (int k = 1; k < 7; ++k)
            acc = fadd(acc, fmul(gw.w[k], g[refl(i - 3 + k, 28) * 28 + j]));
        t[p] = acc;
    }
    __syncthreads();
    for (int p = tid; p < HW; p += 256) {
        int i = p / 28, j = p - (p / 28) * 28;
        float acc = fmul(gw.w[0], t[i * 28 + refl(j - 3, 28)]);
        #pragma unroll
        for (int k = 1; k < 7; ++k)
            acc = fadd(acc, fmul(gw.w[k], t[i * 28 + refl(j - 3 + k, 28)]));
        dout[p] = fabsf(fsub(acc, xl[p]));
    }
    __syncthreads();
}

__global__ void init_kernel(unsigned int* dmax) { *dmax = 0u; }

__global__ __launch_bounds__(256) void dmax_kernel(const float* __restrict__ x,
                                                   int nbatch, GaussW gw,
                                                   unsigned int* __restrict__ dmax) {
    __shared__ float g[HW], t[HW], xl[HW], d[HW];
    __shared__ float wred[4];
    int tid = threadIdx.x;
    dog_sample(x, blockIdx.x, nbatch, gw, g, t, xl, d, tid);
    float m = 0.f;
    for (int p = tid; p < HW; p += 256) m = fmaxf(m, d[p]);
    #pragma unroll
    for (int off = 32; off; off >>= 1) m = fmaxf(m, __shfl_down(m, off, 64));
    if ((tid & 63) == 0) wred[tid >> 6] = m;
    __syncthreads();
    if (tid == 0) {
        m = fmaxf(fmaxf(wred[0], wred[1]), fmaxf(wred[2], wred[3]));
        atomicMax(dmax, __float_as_uint(m));  // d >= 0 so bit-max == float-max
    }
}

__global__ __launch_bounds__(256) void sim_kernel(const float* __restrict__ x,
        int nbatch,
        const float* __restrict__ w1g, const float* __restrict__ w2g,
        const float* __restrict__ w3g, GaussW gw,
        const unsigned int* __restrict__ dmaxp, float* __restrict__ out) {
    __shared__ float dn[HW];        // normalized DoG (layer-1 input current)
    __shared__ float v1[HW];        // IF layer 1 membrane
    __shared__ float s1[HW];        // layer-1 spikes (xl scratch during DoG)
    __shared__ float v2[2704];      // 4x26x26 (first 1568 reused as DoG scratch)
    __shared__ float p1[676];       // 4x13x13 pooled spikes
    __shared__ float v3[484];       // 4x11x11
    __shared__ float p2[144];       // 4x6x6 pooled spikes
    __shared__ float wts[216];      // w1(36) | w2(144) | w3(36)

    int tid = threadIdx.x;
    int b = blockIdx.x;

    dog_sample(x, b, nbatch, gw, v2, v2 + HW, s1, dn, tid);

    float dmax = __uint_as_float(*dmaxp);
    for (int p = tid; p < HW; p += 256) dn[p] = __fdiv_rn(dn[p], dmax);

    if (tid < 36)  wts[tid]       = w1g[tid];
    if (tid < 144) wts[36 + tid]  = w2g[tid];
    if (tid < 36)  wts[180 + tid] = w3g[tid];

    for (int p = tid; p < HW;   p += 256) v1[p] = 0.f;
    for (int p = tid; p < 2704; p += 256) v2[p] = 0.f;
    for (int p = tid; p < 484;  p += 256) v3[p] = 0.f;
    float v4 = 0.f, pred = 0.f;
    __syncthreads();

    for (int step = 0; step < TSTEPS; ++step) {
        // ---- layer 1: IF(4.5) on constant input dn ----
        for (int p = tid; p < HW; p += 256) {
            float v = fadd(v1[p], dn[p]);
            bool sp = v >= 4.5f;
            s1[p] = sp ? 1.f : 0.f;
            v1[p] = sp ? 0.f : v;
        }
        __syncthreads();

        // ---- conv1 (1->4, 3x3, VALID) + IF(4.5) + maxpool2 -> p1[4][13][13] ----
        for (int idx = tid; idx < 676; idx += 256) {
            int c = idx / 169;
            int r = idx - c * 169;
            int pi = r / 13, pj = r - (r / 13) * 13;
            int oi0 = pi * 2, oj0 = pj * 2;
            float sp_[4][4];
            #pragma unroll
            for (int a = 0; a < 4; ++a)
                #pragma unroll
                for (int bb = 0; bb < 4; ++bb)
                    sp_[a][bb] = s1[(oi0 + a) * 28 + oj0 + bb];
            float mx = 0.f;
            #pragma unroll
            for (int di = 0; di < 2; ++di)
            #pragma unroll
            for (int dj = 0; dj < 2; ++dj) {
                float acc = 0.f;
                #pragma unroll
                for (int ki = 0; ki < 3; ++ki)
                #pragma unroll
                for (int kj = 0; kj < 3; ++kj)
                    acc = fadd(acc, fmul(wts[c * 9 + ki * 3 + kj], sp_[di + ki][dj + kj]));
                int vi = c * 676 + (oi0 + di) * 26 + (oj0 + dj);
                float v = fadd(v2[vi], acc);
                bool sp = v >= 4.5f;
                v2[vi] = sp ? 0.f : v;
                mx = fmaxf(mx, sp ? 1.f : 0.f);
            }
            p1[idx] = mx;
        }
        __syncthreads();

        // ---- conv2 (4->4) + IF(1.0) + maxpool2(pad=1) -> p2[4][6][6] ----
        if (tid < 144) {
            int c = tid / 36;
            int r = tid - c * 36;
            int pi = r / 6, pj = r - (r / 6) * 6;
            int r30 = pi * 2 - 1, c30 = pj * 2 - 1;
            float acc[2][2] = {{0.f, 0.f}, {0.f, 0.f}};
            #pragma unroll
            for (int ic = 0; ic < 4; ++ic) {
                float patch[4][4];
                #pragma unroll
                for (int a = 0; a < 4; ++a)
                    #pragma unroll
                    for (int bb = 0; bb < 4; ++bb) {
                        int rr = r30 + a, cc = c30 + bb;
                        patch[a][bb] = ((unsigned)rr < 13u && (unsigned)cc < 13u)
                                       ? p1[ic * 169 + rr * 13 + cc] : 0.f;
                    }
                #pragma unroll
                for (int di = 0; di < 2; ++di)
                #pragma unroll
                for (int dj = 0; dj < 2; ++dj)
                    #pragma unroll
                    for (int ki = 0; ki < 3; ++ki)
                    #pragma unroll
                    for (int kj = 0; kj < 3; ++kj)
                        acc[di][dj] = fadd(acc[di][dj],
                                           fmul(wts[36 + c * 36 + ic * 9 + ki * 3 + kj],
                                                patch[di + ki][dj + kj]));
            }
            float mx = 0.f;
            #pragma unroll
            for (int di = 0; di < 2; ++di)
            #pragma unroll
            for (int dj = 0; dj < 2; ++dj) {
                int r3 = r30 + di, c3 = c30 + dj;
                if ((unsigned)r3 < 11u && (unsigned)c3 < 11u) {
                    int vi = c * 121 + r3 * 11 + c3;
                    float v = fadd(v3[vi], acc[di][dj]);
                    bool sp = v >= 1.0f;
                    v3[vi] = sp ? 0.f : v;
                    mx = fmaxf(mx, sp ? 1.f : 0.f);
                }
            }
            p2[tid] = mx;
        }
        __syncthreads();

        // ---- conv3 (4->1) + LIF(tau=2, decay_input, hard reset) ----
        if (tid < 16) {
            int rr = tid >> 2, cc = tid & 3;
            float acc = 0.f;
            #pragma unroll
            for (int ic = 0; ic < 4; ++ic)
            #pragma unroll
            for (int ki = 0; ki < 3; ++ki)
            #pragma unroll
            for (int kj = 0; kj < 3; ++kj)
                acc = fadd(acc, fmul(wts[180 + ic * 9 + ki * 3 + kj],
                                     p2[ic * 36 + (rr + ki) * 6 + (cc + kj)]));
            // v4 = v4 + (acc - v4)/2  ; /2 == *0.5 exactly
            v4 = fadd(v4, fmul(fsub(acc, v4), 0.5f));
            if (v4 >= 1.0f) { pred += 1.f; v4 = 0.f; }
        }
        __syncthreads();
    }

    if (tid < 16) out[(size_t)b * 16 + tid] = __fdiv_rn(pred, 30.0f);
}

extern "C" void kernel_launch(void* const* d_in, const int* in_sizes, int n_in,
                              void* d_out, int out_size, void* d_ws, size_t ws_size,
                              hipStream_t stream) {
    const float* x  = (const float*)d_in[0];
    const float* w1 = (const float*)d_in[1];
    const float* w2 = (const float*)d_in[2];
    const float* w3 = (const float*)d_in[3];
    float* out = (float*)d_out;
    unsigned int* dmax = (unsigned int*)d_ws;

    int nbatch = in_sizes[0] / HW;

    // Emulate numpy f32: i=arange(-3,4,f32); t=-0.5*(i/2)^2 (exact in f32);
    // exp via CR double->f32; sequential f32 sum (numpy n<8 path); f32 divide.
    GaussW gw;
    {
        float fw[7];
        for (int k = 0; k < 7; ++k) {
            float iv = (float)(k - 3);
            float q = iv / 2.0f;          // exact
            float e = -0.5f * (q * q);    // exact
            fw[k] = (float)exp((double)e); // correctly-rounded f32 exp
        }
        float s = 0.0f;
        for (int k = 0; k < 7; ++k) s += fw[k];  // sequential f32 adds
        for (int k = 0; k < 7; ++k) gw.w[k] = fw[k] / s;  // f32 divide
    }

    hipLaunchKernelGGL(init_kernel, dim3(1), dim3(1), 0, stream, dmax);
    hipLaunchKernelGGL(dmax_kernel, dim3(nbatch), dim3(256), 0, stream,
                       x, nbatch, gw, dmax);
    hipLaunchKernelGGL(sim_kernel, dim3(nbatch), dim3(256), 0, stream,
                       x, nbatch, w1, w2, w3, gw, dmax, out);
}

// Round 4
// 681.526 us; speedup vs baseline: 1.0917x; 1.0917x over previous
//
#include <hip/hip_runtime.h>
#include <math.h>

#define HW 784      // 28*28
#define TSTEPS 30

struct GaussW { float w[7]; };

// Exact-rounded f32 ops (never fused/contracted) to bitwise-match numpy f32.
__device__ __forceinline__ float fadd(float a, float b) { return __fadd_rn(a, b); }
__device__ __forceinline__ float fmul(float a, float b) { return __fmul_rn(a, b); }
__device__ __forceinline__ float fsub(float a, float b) { return __fsub_rn(a, b); }

__device__ __forceinline__ int refl(int i, int n) {
    // numpy 'symmetric' pad mapping for i in [-3, n+2]
    if (i < 0) return -i - 1;
    if (i >= n) return 2 * n - 1 - i;
    return i;
}

// d[p] = |gauss4d(x)[b,p] - x[b,p]| into dout (LDS, 784 floats), bit-exact
// numpy-f32 order: axis0 (batch), axis1 (size-1 channel), axis2, axis3.
__device__ void dog_sample(const float* __restrict__ x, int b, int nbatch,
                           const GaussW gw, float* g, float* t, float* xl,
                           float* dout, int tid) {
    for (int p = tid; p < HW; p += 256) {
        float acc = fmul(gw.w[0], x[(size_t)refl(b - 3, nbatch) * HW + p]);
        #pragma unroll
        for (int k = 1; k < 7; ++k)
            acc = fadd(acc, fmul(gw.w[k], x[(size_t)refl(b - 3 + k, nbatch) * HW + p]));
        float h = fmul(gw.w[0], acc);   // axis 1: size-1 dim, all slices equal
        #pragma unroll
        for (int k = 1; k < 7; ++k)
            h = fadd(h, fmul(gw.w[k], acc));
        g[p] = h;
        xl[p] = x[(size_t)b * HW + p];
    }
    __syncthreads();
    for (int p = tid; p < HW; p += 256) {
        int i = p / 28, j = p - (p / 28) * 28;
        float acc = fmul(gw.w[0], g[refl(i - 3, 28) * 28 + j]);
        #pragma unroll
        for (int k = 1; k < 7; ++k)
            acc = fadd(acc, fmul(gw.w[k], g[refl(i - 3 + k, 28) * 28 + j]));
        t[p] = acc;
    }
    __syncthreads();
    for (int p = tid; p < HW; p += 256) {
        int i = p / 28, j = p - (p / 28) * 28;
        float acc = fmul(gw.w[0], t[i * 28 + refl(j - 3, 28)]);
        #pragma unroll
        for (int k = 1; k < 7; ++k)
            acc = fadd(acc, fmul(gw.w[k], t[i * 28 + refl(j - 3 + k, 28)]));
        dout[p] = fabsf(fsub(acc, xl[p]));
    }
    __syncthreads();
}

__global__ void init_kernel(unsigned int* dmax) { *dmax = 0u; }

template<bool CACHE>
__global__ __launch_bounds__(256) void dmax_kernel(const float* __restrict__ x,
                                                   int nbatch, GaussW gw,
                                                   unsigned int* __restrict__ dmax,
                                                   float* __restrict__ dcache) {
    __shared__ float g[HW], t[HW], xl[HW], d[HW];
    __shared__ float wred[4];
    int tid = threadIdx.x;
    int b = blockIdx.x;
    dog_sample(x, b, nbatch, gw, g, t, xl, d, tid);
    if (CACHE)
        for (int p = tid; p < HW; p += 256) dcache[(size_t)b * HW + p] = d[p];
    float m = 0.f;
    for (int p = tid; p < HW; p += 256) m = fmaxf(m, d[p]);
    #pragma unroll
    for (int off = 32; off; off >>= 1) m = fmaxf(m, __shfl_down(m, off, 64));
    if ((tid & 63) == 0) wred[tid >> 6] = m;
    __syncthreads();
    if (tid == 0) {
        m = fmaxf(fmaxf(wred[0], wred[1]), fmaxf(wred[2], wred[3]));
        atomicMax(dmax, __float_as_uint(m));  // d >= 0 so bit-max == float-max
    }
}

template<bool CACHE>
__global__ __launch_bounds__(256) void sim_kernel(const float* __restrict__ x,
        int nbatch,
        const float* __restrict__ w1g, const float* __restrict__ w2g,
        const float* __restrict__ w3g, GaussW gw,
        const unsigned int* __restrict__ dmaxp,
        const float* __restrict__ dcache,
        float* __restrict__ out) {
    __shared__ __align__(16) float dn[HW];     // normalized DoG input current
    __shared__ __align__(16) float v1[HW];     // IF layer-1 membrane
    __shared__ __align__(16) float s1[HW];     // layer-1 spikes (xl scratch in DoG)
    __shared__ __align__(16) float v2[2704];   // 4x26x26 (first 1568 = DoG scratch)
    __shared__ __align__(16) float p1[784];    // pooled spikes, padded [4][14][14]
    __shared__ __align__(16) float v3[484];    // 4x11x11
    __shared__ __align__(16) float p2[144];    // 4x6x6
    __shared__ __align__(16) float wts[216];   // w1(36) | w2(144) | w3(36)

    int tid = threadIdx.x;
    int b = blockIdx.x;

    if (CACHE) {
        for (int p = tid; p < HW; p += 256) dn[p] = dcache[(size_t)b * HW + p];
    } else {
        dog_sample(x, b, nbatch, gw, v2, v2 + HW, s1, dn, tid);
    }

    float dmax = __uint_as_float(*dmaxp);
    for (int p = tid; p < HW; p += 256) dn[p] = __fdiv_rn(dn[p], dmax);

    if (tid < 36)  wts[tid]       = w1g[tid];
    if (tid < 144) wts[36 + tid]  = w2g[tid];
    if (tid < 36)  wts[180 + tid] = w3g[tid];

    for (int p = tid; p < HW;   p += 256) v1[p] = 0.f;
    for (int p = tid; p < 2704; p += 256) v2[p] = 0.f;
    for (int p = tid; p < 784;  p += 256) p1[p] = 0.f;  // borders stay 0 forever
    for (int p = tid; p < 484;  p += 256) v3[p] = 0.f;
    float v4 = 0.f, pred = 0.f;
    __syncthreads();

    // layer1(0) by all threads
    for (int p = tid; p < HW; p += 256) {
        float v = fadd(v1[p], dn[p]);
        bool sp = v >= 4.5f;
        s1[p] = sp ? 1.f : 0.f;
        v1[p] = sp ? 0.f : v;
    }
    __syncthreads();

    for (int t = 0; t < TSTEPS; ++t) {
        // ======== phase B: conv3(t-1) [lanes 240..255] + conv1(t) [all] ========
        if (t > 0 && tid >= 240) {
            int q = tid - 240;
            int rr = q >> 2, cc = q & 3;
            float acc = 0.f;
            #pragma unroll
            for (int ic = 0; ic < 4; ++ic)
                #pragma unroll
                for (int ki = 0; ki < 3; ++ki)
                    #pragma unroll
                    for (int kj = 0; kj < 3; ++kj)
                        acc = fadd(acc, fmul(wts[180 + ic * 9 + ki * 3 + kj],
                                             p2[ic * 36 + (rr + ki) * 6 + cc + kj]));
            v4 = fadd(v4, fmul(fsub(acc, v4), 0.5f));
            if (v4 >= 1.0f) { pred += 1.f; v4 = 0.f; }
        }
        // conv1 (1->4, 3x3) + IF(4.5) + maxpool2, one pooled cell per item
        for (int idx = tid; idx < 676; idx += 256) {
            int c = idx / 169;
            int r = idx - c * 169;
            int pi = r / 13, pj = r - (r / 13) * 13;
            int oi0 = pi * 2, oj0 = pj * 2;
            float sp_[4][4];
            #pragma unroll
            for (int a = 0; a < 4; ++a) {
                const float2* rp = reinterpret_cast<const float2*>(
                    &s1[(oi0 + a) * 28 + oj0]);
                float2 u0 = rp[0], u1 = rp[1];
                sp_[a][0] = u0.x; sp_[a][1] = u0.y;
                sp_[a][2] = u1.x; sp_[a][3] = u1.y;
            }
            const float* wc = &wts[c * 9];
            float mx = 0.f;
            #pragma unroll
            for (int di = 0; di < 2; ++di) {
                int vbase = c * 676 + (oi0 + di) * 26 + oj0;
                float2 vv = *reinterpret_cast<const float2*>(&v2[vbase]);
                float vr0 = vv.x, vr1 = vv.y;
                #pragma unroll
                for (int dj = 0; dj < 2; ++dj) {
                    float acc = 0.f;
                    #pragma unroll
                    for (int ki = 0; ki < 3; ++ki)
                        #pragma unroll
                        for (int kj = 0; kj < 3; ++kj)
                            acc = fadd(acc, fmul(wc[ki * 3 + kj],
                                                 sp_[di + ki][dj + kj]));
                    float v = fadd(dj == 0 ? vr0 : vr1, acc);
                    bool sp = v >= 4.5f;
                    float nv = sp ? 0.f : v;
                    if (dj == 0) vr0 = nv; else vr1 = nv;
                    mx = fmaxf(mx, sp ? 1.f : 0.f);
                }
                vv.x = vr0; vv.y = vr1;
                *reinterpret_cast<float2*>(&v2[vbase]) = vv;
            }
            p1[c * 196 + (pi + 1) * 14 + (pj + 1)] = mx;   // padded [4][14][14]
        }
        __syncthreads();

        // ======== phase A: conv2(t) [tid<144] || layer1(t+1) [tid>=144] ========
        if (tid < 144) {
            int c = tid / 36;
            int r = tid - c * 36;
            int pi = r / 6, pj = r - (r / 6) * 6;
            int r30 = pi * 2 - 1, c30 = pj * 2 - 1;
            float acc[2][2] = {{0.f, 0.f}, {0.f, 0.f}};
            const float* wcc = &wts[36 + c * 36];
            #pragma unroll
            for (int ic = 0; ic < 4; ++ic) {
                float patch[4][4];
                #pragma unroll
                for (int a = 0; a < 4; ++a) {
                    const float2* rp = reinterpret_cast<const float2*>(
                        &p1[ic * 196 + (r30 + a + 1) * 14 + (c30 + 1)]);
                    float2 u0 = rp[0], u1 = rp[1];
                    patch[a][0] = u0.x; patch[a][1] = u0.y;
                    patch[a][2] = u1.x; patch[a][3] = u1.y;
                }
                #pragma unroll
                for (int di = 0; di < 2; ++di)
                #pragma unroll
                for (int dj = 0; dj < 2; ++dj)
                    #pragma unroll
                    for (int ki = 0; ki < 3; ++ki)
                    #pragma unroll
                    for (int kj = 0; kj < 3; ++kj)
                        acc[di][dj] = fadd(acc[di][dj],
                                           fmul(wcc[ic * 9 + ki * 3 + kj],
                                                patch[di + ki][dj + kj]));
            }
            float mx = 0.f;
            #pragma unroll
            for (int di = 0; di < 2; ++di)
            #pragma unroll
            for (int dj = 0; dj < 2; ++dj) {
                int r3 = r30 + di, c3 = c30 + dj;
                if ((unsigned)r3 < 11u && (unsigned)c3 < 11u) {
                    int vi = c * 121 + r3 * 11 + c3;
                    float v = fadd(v3[vi], acc[di][dj]);
                    bool sp = v >= 1.0f;
                    v3[vi] = sp ? 0.f : v;
                    mx = fmaxf(mx, sp ? 1.f : 0.f);
                }
            }
            p2[tid] = mx;
        } else if (t < TSTEPS - 1) {
            for (int p = tid - 144; p < HW; p += 112) {
                float v = fadd(v1[p], dn[p]);
                bool sp = v >= 4.5f;
                s1[p] = sp ? 1.f : 0.f;
                v1[p] = sp ? 0.f : v;
            }
        }
        __syncthreads();
    }

    // epilogue: conv3(29) + output
    if (tid >= 240) {
        int q = tid - 240;
        int rr = q >> 2, cc = q & 3;
        float acc = 0.f;
        #pragma unroll
        for (int ic = 0; ic < 4; ++ic)
            #pragma unroll
            for (int ki = 0; ki < 3; ++ki)
                #pragma unroll
                for (int kj = 0; kj < 3; ++kj)
                    acc = fadd(acc, fmul(wts[180 + ic * 9 + ki * 3 + kj],
                                         p2[ic * 36 + (rr + ki) * 6 + cc + kj]));
        v4 = fadd(v4, fmul(fsub(acc, v4), 0.5f));
        if (v4 >= 1.0f) { pred += 1.f; v4 = 0.f; }
        out[(size_t)b * 16 + q] = __fdiv_rn(pred, 30.0f);
    }
}

extern "C" void kernel_launch(void* const* d_in, const int* in_sizes, int n_in,
                              void* d_out, int out_size, void* d_ws, size_t ws_size,
                              hipStream_t stream) {
    const float* x  = (const float*)d_in[0];
    const float* w1 = (const float*)d_in[1];
    const float* w2 = (const float*)d_in[2];
    const float* w3 = (const float*)d_in[3];
    float* out = (float*)d_out;
    unsigned int* dmax = (unsigned int*)d_ws;
    float* dcache = (float*)((char*)d_ws + 16);

    int nbatch = in_sizes[0] / HW;
    size_t need = 16 + (size_t)nbatch * HW * sizeof(float);
    bool cache = ws_size >= need;

    // numpy-f32 Gaussian weights: exact f32 steps + correctly-rounded exp
    GaussW gw;
    {
        float fw[7];
        for (int k = 0; k < 7; ++k) {
            float iv = (float)(k - 3);
            float q = iv / 2.0f;
            float e = -0.5f * (q * q);
            fw[k] = (float)exp((double)e);
        }
        float s = 0.0f;
        for (int k = 0; k < 7; ++k) s += fw[k];
        for (int k = 0; k < 7; ++k) gw.w[k] = fw[k] / s;
    }

    hipLaunchKernelGGL(init_kernel, dim3(1), dim3(1), 0, stream, dmax);
    if (cache) {
        hipLaunchKernelGGL(dmax_kernel<true>, dim3(nbatch), dim3(256), 0, stream,
                           x, nbatch, gw, dmax, dcache);
        hipLaunchKernelGGL(sim_kernel<true>, dim3(nbatch), dim3(256), 0, stream,
                           x, nbatch, w1, w2, w3, gw, dmax, dcache, out);
    } else {
        hipLaunchKernelGGL(dmax_kernel<false>, dim3(nbatch), dim3(256), 0, stream,
                           x, nbatch, gw, dmax, dcache);
        hipLaunchKernelGGL(sim_kernel<false>, dim3(nbatch), dim3(256), 0, stream,
                           x, nbatch, w1, w2, w3, gw, dmax, dcache, out);
    }
}

// Round 5
// 650.166 us; speedup vs baseline: 1.1444x; 1.0482x over previous
//
#include <hip/hip_runtime.h>
#include <math.h>

#define HW 784      // 28*28
#define TSTEPS 30

struct GaussW { float w[7]; };

// Exact-rounded f32 ops (never fused/contracted) to bitwise-match numpy f32.
__device__ __forceinline__ float fadd(float a, float b) { return __fadd_rn(a, b); }
__device__ __forceinline__ float fmul(float a, float b) { return __fmul_rn(a, b); }
__device__ __forceinline__ float fsub(float a, float b) { return __fsub_rn(a, b); }

__device__ __forceinline__ int refl(int i, int n) {
    // numpy 'symmetric' pad mapping for i in [-3, n+2]
    if (i < 0) return -i - 1;
    if (i >= n) return 2 * n - 1 - i;
    return i;
}

// d[p] = |gauss4d(x)[b,p] - x[b,p]| into dout (784 floats in LDS), bit-exact
// numpy-f32 order: axis0 (batch), axis1 (size-1 channel), axis2, axis3.
__device__ void dog_sample(const float* __restrict__ x, int b, int nbatch,
                           const GaussW gw, float* g, float* t,
                           float* dout, int tid) {
    for (int p = tid; p < HW; p += 256) {
        float acc = fmul(gw.w[0], x[(size_t)refl(b - 3, nbatch) * HW + p]);
        #pragma unroll
        for (int k = 1; k < 7; ++k)
            acc = fadd(acc, fmul(gw.w[k], x[(size_t)refl(b - 3 + k, nbatch) * HW + p]));
        float h = fmul(gw.w[0], acc);   // axis 1: size-1 dim, all slices equal
        #pragma unroll
        for (int k = 1; k < 7; ++k)
            h = fadd(h, fmul(gw.w[k], acc));
        g[p] = h;
    }
    __syncthreads();
    for (int p = tid; p < HW; p += 256) {
        int i = p / 28, j = p - (p / 28) * 28;
        float acc = fmul(gw.w[0], g[refl(i - 3, 28) * 28 + j]);
        #pragma unroll
        for (int k = 1; k < 7; ++k)
            acc = fadd(acc, fmul(gw.w[k], g[refl(i - 3 + k, 28) * 28 + j]));
        t[p] = acc;
    }
    __syncthreads();
    for (int p = tid; p < HW; p += 256) {
        int i = p / 28, j = p - (p / 28) * 28;
        float acc = fmul(gw.w[0], t[i * 28 + refl(j - 3, 28)]);
        #pragma unroll
        for (int k = 1; k < 7; ++k)
            acc = fadd(acc, fmul(gw.w[k], t[i * 28 + refl(j - 3 + k, 28)]));
        dout[p] = fabsf(fsub(acc, x[(size_t)b * HW + p]));
    }
    __syncthreads();
}

__global__ void init_kernel(unsigned int* dmax) { *dmax = 0u; }

template<bool CACHE>
__global__ __launch_bounds__(256) void dmax_kernel(const float* __restrict__ x,
                                                   int nbatch, GaussW gw,
                                                   unsigned int* __restrict__ dmax,
                                                   float* __restrict__ dcache) {
    __shared__ float g[HW], t[HW], d[HW];
    __shared__ float wred[4];
    int tid = threadIdx.x;
    int b = blockIdx.x;
    dog_sample(x, b, nbatch, gw, g, t, d, tid);
    if (CACHE)
        for (int p = tid; p < HW; p += 256) dcache[(size_t)b * HW + p] = d[p];
    float m = 0.f;
    for (int p = tid; p < HW; p += 256) m = fmaxf(m, d[p]);
    #pragma unroll
    for (int off = 32; off; off >>= 1) m = fmaxf(m, __shfl_down(m, off, 64));
    if ((tid & 63) == 0) wred[tid >> 6] = m;
    __syncthreads();
    if (tid == 0) {
        m = fmaxf(fmaxf(wred[0], wred[1]), fmaxf(wred[2], wred[3]));
        atomicMax(dmax, __float_as_uint(m));  // d >= 0 so bit-max == float-max
    }
}

template<bool CACHE>
__global__ __launch_bounds__(256) void sim_kernel(const float* __restrict__ x,
        int nbatch,
        const float* __restrict__ w1g, const float* __restrict__ w2g,
        const float* __restrict__ w3g, GaussW gw,
        const unsigned int* __restrict__ dmaxp,
        const float* __restrict__ dcache,
        float* __restrict__ out) {
    __shared__ __align__(16) float4 lut[512];     // conv1 LUT[pattern]=4ch sums; DoG scratch
    __shared__ __align__(16) float dn[HW];        // normalized DoG input current
    __shared__ unsigned s1m[2][28];               // layer-1 spike row masks (dbuf)
    __shared__ unsigned p1m[2][52];               // pooled-1 masks [4ch][13rows], bits<<1 (dbuf)
    __shared__ float p2[144];                     // pooled-2 spikes (float 0/1)
    __shared__ float wts[216];                    // w1(36) | w2(144) | w3(36)

    int tid = threadIdx.x;
    int b = blockIdx.x;

    // ---- per-thread persistent state (registers) ----
    float v2r[4][2][2] = {};   // conv1 membrane quad, threads 0..168 (pi,pj)
    float v3r[2][2]    = {};   // conv2 membrane quad, threads 0..143 (c,pi,pj)
    float v1r[7]       = {};   // layer-1 membranes, threads 144..255
    float v4 = 0.f, pred = 0.f; // LIF, threads 240..255

    // thread geometry
    int pi1 = tid / 13, pj1 = tid - pi1 * 13;          // conv1 (tid<169)
    int c2  = tid / 36;                                 // conv2 (tid<144)
    int r2  = tid - c2 * 36;
    int pi2 = r2 / 6, pj2 = r2 - pi2 * 6;
    int base = tid - 144;                               // layer1 (tid>=144)
    int row0 = base / 28, col1 = base - (base / 28) * 28;
    unsigned colbit = 1u << col1;

    // ---- init phase 0: weights + dn ----
    if (tid < 36)  wts[tid]       = w1g[tid];
    if (tid < 144) wts[36 + tid]  = w2g[tid];
    if (tid < 36)  wts[180 + tid] = w3g[tid];
    float dmax = __uint_as_float(*dmaxp);
    if (CACHE) {
        for (int p = tid; p < HW; p += 256)
            dn[p] = __fdiv_rn(dcache[(size_t)b * HW + p], dmax);
    } else {
        float* scr = (float*)lut;   // 2048 floats >= 2*784
        dog_sample(x, b, nbatch, gw, scr, scr + HW, dn, tid);
        for (int p = tid; p < HW; p += 256) dn[p] = __fdiv_rn(dn[p], dmax);
    }
    __syncthreads();

    // ---- init phase 1: conv1 LUT (bit-exact fadd-fold) + zero masks ----
    for (int e = tid; e < 512; e += 256) {
        float a0 = 0.f, a1 = 0.f, a2 = 0.f, a3 = 0.f;
        #pragma unroll
        for (int k = 0; k < 9; ++k) {
            bool bit = (e >> k) & 1;
            a0 = fadd(a0, bit ? wts[k]      : 0.0f);
            a1 = fadd(a1, bit ? wts[9 + k]  : 0.0f);
            a2 = fadd(a2, bit ? wts[18 + k] : 0.0f);
            a3 = fadd(a3, bit ? wts[27 + k] : 0.0f);
        }
        lut[e] = make_float4(a0, a1, a2, a3);
    }
    if (tid < 28) s1m[0][tid] = 0u;
    else if (tid < 80) p1m[0][tid - 28] = 0u;
    __syncthreads();

    // ---- init phase 2: layer1(0) -> s1m[0] ----
    if (tid >= 144) {
        #pragma unroll
        for (int k = 0; k < 7; ++k) {
            float v = fadd(v1r[k], dn[base + 112 * k]);
            bool s = v >= 4.5f;
            v1r[k] = s ? 0.f : v;
            if (s) atomicOr(&s1m[0][row0 + 4 * k], colbit);
        }
    }
    __syncthreads();

    for (int t = 0; t < TSTEPS; ++t) {
        // ======== phase B: conv1(t) | zero next masks | conv3(t-1) ========
        if (tid < 169) {
            const unsigned* sm = s1m[t & 1];
            int oi0 = 2 * pi1, oj0 = 2 * pj1;
            unsigned m0 = sm[oi0], m1 = sm[oi0 + 1], m2 = sm[oi0 + 2], m3 = sm[oi0 + 3];
            unsigned cb0 = 0, cb1 = 0, cb2 = 0, cb3 = 0;
            #pragma unroll
            for (int di = 0; di < 2; ++di) {
                unsigned ra = di ? m1 : m0;
                unsigned rb = di ? m2 : m1;
                unsigned rc = di ? m3 : m2;
                #pragma unroll
                for (int dj = 0; dj < 2; ++dj) {
                    unsigned sh = (unsigned)(oj0 + dj);
                    unsigned pat = ((ra >> sh) & 7u) | (((rb >> sh) & 7u) << 3)
                                 | (((rc >> sh) & 7u) << 6);
                    float4 a4 = lut[pat];
                    { float v = fadd(v2r[0][di][dj], a4.x); bool s = v >= 4.5f;
                      v2r[0][di][dj] = s ? 0.f : v; cb0 |= (unsigned)s; }
                    { float v = fadd(v2r[1][di][dj], a4.y); bool s = v >= 4.5f;
                      v2r[1][di][dj] = s ? 0.f : v; cb1 |= (unsigned)s; }
                    { float v = fadd(v2r[2][di][dj], a4.z); bool s = v >= 4.5f;
                      v2r[2][di][dj] = s ? 0.f : v; cb2 |= (unsigned)s; }
                    { float v = fadd(v2r[3][di][dj], a4.w); bool s = v >= 4.5f;
                      v2r[3][di][dj] = s ? 0.f : v; cb3 |= (unsigned)s; }
                }
            }
            unsigned* pm = p1m[t & 1];
            unsigned bitp = 1u << (pj1 + 1);   // pre-shifted by 1 (pad-left)
            if (cb0) atomicOr(&pm[pi1],      bitp);
            if (cb1) atomicOr(&pm[13 + pi1], bitp);
            if (cb2) atomicOr(&pm[26 + pi1], bitp);
            if (cb3) atomicOr(&pm[39 + pi1], bitp);
        } else if (tid < 240) {
            unsigned* sn = s1m[(t + 1) & 1];
            unsigned* pn = p1m[(t + 1) & 1];
            for (int w = tid - 169; w < 80; w += 71) {
                if (w < 28) sn[w] = 0u; else pn[w - 28] = 0u;
            }
        } else if (t > 0) {
            int q = tid - 240;
            int rr = q >> 2, cc = q & 3;
            float acc = 0.f;
            #pragma unroll
            for (int ic = 0; ic < 4; ++ic)
                #pragma unroll
                for (int ki = 0; ki < 3; ++ki)
                    #pragma unroll
                    for (int kj = 0; kj < 3; ++kj)
                        acc = fadd(acc, fmul(wts[180 + ic * 9 + ki * 3 + kj],
                                             p2[ic * 36 + (rr + ki) * 6 + cc + kj]));
            v4 = fadd(v4, fmul(fsub(acc, v4), 0.5f));
            if (v4 >= 1.0f) { pred += 1.f; v4 = 0.f; }
        }
        __syncthreads();

        // ======== phase A: conv2(t) [tid<144] || layer1(t+1) [tid>=144] ========
        if (tid < 144) {
            const unsigned* pm = p1m[t & 1];
            int r30 = 2 * pi2 - 1;
            unsigned rows[4][4];
            #pragma unroll
            for (int ic = 0; ic < 4; ++ic)
                #pragma unroll
                for (int a = 0; a < 4; ++a) {
                    int rr = r30 + a;                 // -1..12
                    rows[ic][a] = (rr >= 0) ? pm[ic * 13 + rr] : 0u;
                }
            const float* wcc = &wts[36 + c2 * 36];
            unsigned anyspike = 0;
            #pragma unroll
            for (int di = 0; di < 2; ++di)
            #pragma unroll
            for (int dj = 0; dj < 2; ++dj) {
                int r3 = r30 + di, c3 = 2 * pj2 - 1 + dj;   // max 10, min -1
                if (r3 >= 0 && c3 >= 0) {
                    float acc = 0.f;
                    #pragma unroll
                    for (int ic = 0; ic < 4; ++ic)
                        #pragma unroll
                        for (int ki = 0; ki < 3; ++ki) {
                            unsigned rw = rows[ic][di + ki] >> (unsigned)(c3 + 1);
                            #pragma unroll
                            for (int kj = 0; kj < 3; ++kj)
                                acc = fadd(acc, ((rw >> kj) & 1u)
                                                ? wcc[ic * 9 + ki * 3 + kj] : 0.0f);
                        }
                    float v = fadd(v3r[di][dj], acc);
                    bool s = v >= 1.0f;
                    v3r[di][dj] = s ? 0.f : v;
                    anyspike |= (unsigned)s;
                }
            }
            p2[tid] = anyspike ? 1.f : 0.f;
        } else if (t < TSTEPS - 1) {
            unsigned* smn = s1m[(t + 1) & 1];
            #pragma unroll
            for (int k = 0; k < 7; ++k) {
                float v = fadd(v1r[k], dn[base + 112 * k]);
                bool s = v >= 4.5f;
                v1r[k] = s ? 0.f : v;
                if (s) atomicOr(&smn[row0 + 4 * k], colbit);
            }
        }
        __syncthreads();
    }

    // epilogue: conv3(29) + output
    if (tid >= 240) {
        int q = tid - 240;
        int rr = q >> 2, cc = q & 3;
        float acc = 0.f;
        #pragma unroll
        for (int ic = 0; ic < 4; ++ic)
            #pragma unroll
            for (int ki = 0; ki < 3; ++ki)
                #pragma unroll
                for (int kj = 0; kj < 3; ++kj)
                    acc = fadd(acc, fmul(wts[180 + ic * 9 + ki * 3 + kj],
                                         p2[ic * 36 + (rr + ki) * 6 + cc + kj]));
        v4 = fadd(v4, fmul(fsub(acc, v4), 0.5f));
        if (v4 >= 1.0f) { pred += 1.f; v4 = 0.f; }
        out[(size_t)b * 16 + q] = __fdiv_rn(pred, 30.0f);
    }
}

extern "C" void kernel_launch(void* const* d_in, const int* in_sizes, int n_in,
                              void* d_out, int out_size, void* d_ws, size_t ws_size,
                              hipStream_t stream) {
    const float* x  = (const float*)d_in[0];
    const float* w1 = (const float*)d_in[1];
    const float* w2 = (const float*)d_in[2];
    const float* w3 = (const float*)d_in[3];
    float* out = (float*)d_out;
    unsigned int* dmax = (unsigned int*)d_ws;
    float* dcache = (float*)((char*)d_ws + 16);

    int nbatch = in_sizes[0] / HW;
    size_t need = 16 + (size_t)nbatch * HW * sizeof(float);
    bool cache = ws_size >= need;

    // numpy-f32 Gaussian weights: exact f32 steps + correctly-rounded exp
    GaussW gw;
    {
        float fw[7];
        for (int k = 0; k < 7; ++k) {
            float iv = (float)(k - 3);
            float q = iv / 2.0f;
            float e = -0.5f * (q * q);
            fw[k] = (float)exp((double)e);
        }
        float s = 0.0f;
        for (int k = 0; k < 7; ++k) s += fw[k];
        for (int k = 0; k < 7; ++k) gw.w[k] = fw[k] / s;
    }

    hipLaunchKernelGGL(init_kernel, dim3(1), dim3(1), 0, stream, dmax);
    if (cache) {
        hipLaunchKernelGGL(dmax_kernel<true>, dim3(nbatch), dim3(256), 0, stream,
                           x, nbatch, gw, dmax, dcache);
        hipLaunchKernelGGL(sim_kernel<true>, dim3(nbatch), dim3(256), 0, stream,
                           x, nbatch, w1, w2, w3, gw, dmax, dcache, out);
    } else {
        hipLaunchKernelGGL(dmax_kernel<false>, dim3(nbatch), dim3(256), 0, stream,
                           x, nbatch, gw, dmax, dcache);
        hipLaunchKernelGGL(sim_kernel<false>, dim3(nbatch), dim3(256), 0, stream,
                           x, nbatch, w1, w2, w3, gw, dmax, dcache, out);
    }
}

// Round 6
// 520.126 us; speedup vs baseline: 1.4305x; 1.2500x over previous
//
#include <hip/hip_runtime.h>
#include <math.h>

#define HW 784      // 28*28
#define TSTEPS 30

struct GaussW { float w[7]; };

// Exact-rounded f32 ops (never fused/contracted) to bitwise-match numpy f32.
__device__ __forceinline__ float fadd(float a, float b) { return __fadd_rn(a, b); }
__device__ __forceinline__ float fmul(float a, float b) { return __fmul_rn(a, b); }
__device__ __forceinline__ float fsub(float a, float b) { return __fsub_rn(a, b); }

// w if bit kj of rw is set, else +0.0f  (pure bit ops; fadd(acc, +0)==acc and
// fadd(acc, w) == reference fadd(acc, fmul(w, spike)) bitwise for spike in {0,1})
#define SELW(rw, kj, w) \
    __int_as_float((((int)((rw) << (31 - (kj)))) >> 31) & __float_as_int(w))

__device__ __forceinline__ int refl(int i, int n) {
    if (i < 0) return -i - 1;
    if (i >= n) return 2 * n - 1 - i;
    return i;
}

// d[p] = |gauss4d(x)[b,p] - x[b,p]| into dout (784 floats in LDS), bit-exact
// numpy-f32 order: axis0 (batch), axis1 (size-1 channel), axis2, axis3.
__device__ void dog_sample(const float* __restrict__ x, int b, int nbatch,
                           const GaussW gw, float* g, float* t,
                           float* dout, int tid) {
    for (int p = tid; p < HW; p += 256) {
        float acc = fmul(gw.w[0], x[(size_t)refl(b - 3, nbatch) * HW + p]);
        #pragma unroll
        for (int k = 1; k < 7; ++k)
            acc = fadd(acc, fmul(gw.w[k], x[(size_t)refl(b - 3 + k, nbatch) * HW + p]));
        float h = fmul(gw.w[0], acc);   // axis 1: size-1 dim, all slices equal
        #pragma unroll
        for (int k = 1; k < 7; ++k)
            h = fadd(h, fmul(gw.w[k], acc));
        g[p] = h;
    }
    __syncthreads();
    for (int p = tid; p < HW; p += 256) {
        int i = p / 28, j = p - (p / 28) * 28;
        float acc = fmul(gw.w[0], g[refl(i - 3, 28) * 28 + j]);
        #pragma unroll
        for (int k = 1; k < 7; ++k)
            acc = fadd(acc, fmul(gw.w[k], g[refl(i - 3 + k, 28) * 28 + j]));
        t[p] = acc;
    }
    __syncthreads();
    for (int p = tid; p < HW; p += 256) {
        int i = p / 28, j = p - (p / 28) * 28;
        float acc = fmul(gw.w[0], t[i * 28 + refl(j - 3, 28)]);
        #pragma unroll
        for (int k = 1; k < 7; ++k)
            acc = fadd(acc, fmul(gw.w[k], t[i * 28 + refl(j - 3 + k, 28)]));
        dout[p] = fabsf(fsub(acc, x[(size_t)b * HW + p]));
    }
    __syncthreads();
}

__global__ void init_kernel(unsigned int* dmax) { *dmax = 0u; }

template<bool CACHE>
__global__ __launch_bounds__(256) void dmax_kernel(const float* __restrict__ x,
                                                   int nbatch, GaussW gw,
                                                   unsigned int* __restrict__ dmax,
                                                   float* __restrict__ dcache) {
    __shared__ float g[HW], t[HW], d[HW];
    __shared__ float wred[4];
    int tid = threadIdx.x;
    int b = blockIdx.x;
    dog_sample(x, b, nbatch, gw, g, t, d, tid);
    if (CACHE)
        for (int p = tid; p < HW; p += 256) dcache[(size_t)b * HW + p] = d[p];
    float m = 0.f;
    for (int p = tid; p < HW; p += 256) m = fmaxf(m, d[p]);
    #pragma unroll
    for (int off = 32; off; off >>= 1) m = fmaxf(m, __shfl_down(m, off, 64));
    if ((tid & 63) == 0) wred[tid >> 6] = m;
    __syncthreads();
    if (tid == 0) {
        m = fmaxf(fmaxf(wred[0], wred[1]), fmaxf(wred[2], wred[3]));
        atomicMax(dmax, __float_as_uint(m));  // d >= 0 so bit-max == float-max
    }
}

template<bool CACHE>
__global__ __launch_bounds__(256) void sim_kernel(const float* __restrict__ x,
        int nbatch,
        const float* __restrict__ w1g, const float* __restrict__ w2g,
        const float* __restrict__ w3g, GaussW gw,
        const unsigned int* __restrict__ dmaxp,
        const float* __restrict__ dcache,
        float* __restrict__ out) {
    __shared__ __align__(16) float4 lut[512];   // conv1 LUT; DoG scratch pre-loop
    __shared__ __align__(16) float dn[HW];      // normalized DoG input
    __shared__ unsigned s1m[2][28];             // layer-1 spike row masks (dbuf)
    __shared__ unsigned p1m[2][52];             // pooled-1 masks [4c][13r], bits<<1
    __shared__ unsigned p2m[2][24];             // pooled-2 masks [4c][6r], bits 0..5
    __shared__ float wts[216];                  // w1(36) | w2(144) | w3(36)

    int tid = threadIdx.x;
    int b = blockIdx.x;

    // ---------------- fixed geometry (precomputed, static reg arrays) -------
    // conv1: items e = tid + 256k (k<3, e<676): (c, pooled pi,pj)
    int c1_[3], srow_[3], sh1_[3], pw1_[3]; unsigned pb1_[3];
    #pragma unroll
    for (int k = 0; k < 3; ++k) {
        int e = tid + (k << 8); if (e >= 676) e = 0;   // dummy; guarded at use
        int c = e / 169, r = e - c * 169;
        int pi = r / 13, pj = r - (r / 13) * 13;
        c1_[k] = c; srow_[k] = 2 * pi; sh1_[k] = 2 * pj;
        pw1_[k] = c * 13 + pi; pb1_[k] = 1u << (pj + 1);
    }
    // conv2: tid<240: c=tid/60, cells r=2q,2q+1 (q=tid%60); tid 240..243: c=tid-240, r=120
    bool cv2a = tid < 244, cv2b = tid < 240;
    int c2 = cv2b ? (tid / 60) : (cv2a ? tid - 240 : 0);
    int q2 = cv2b ? (tid - c2 * 60) : 60;
    int prow_[2], jsh_[2], p2w_[2]; unsigned p2b_[2];
    #pragma unroll
    for (int k = 0; k < 2; ++k) {
        int r = 2 * q2 + k; if (r > 120) r = 120;
        int i = r / 11, j = r - (r / 11) * 11;
        prow_[k] = i; jsh_[k] = j + 1;
        p2w_[k] = c2 * 6 + ((i + 1) >> 1); p2b_[k] = 1u << ((j + 1) >> 1);
    }
    // layer1: pixels e = tid + 256k (k<4, e<784)
    int l1w_[4]; unsigned l1b_[4];
    #pragma unroll
    for (int k = 0; k < 4; ++k) {
        int e = tid + (k << 8); if (e >= HW) e = 0;
        int rw = e / 28;
        l1w_[k] = rw; l1b_[k] = 1u << (e - rw * 28);
    }

    // ---------------- membranes (registers) ----------------
    float v2q[3][4] = {{0.f,0.f,0.f,0.f},{0.f,0.f,0.f,0.f},{0.f,0.f,0.f,0.f}};
    float v3m[2] = {0.f, 0.f};
    float v1m[4] = {0.f, 0.f, 0.f, 0.f};
    float v4 = 0.f, pred = 0.f;

    // ---------------- init phase 0: weights + dn ----------------
    if (tid < 36)  wts[tid]       = w1g[tid];
    if (tid < 144) wts[36 + tid]  = w2g[tid];
    if (tid < 36)  wts[180 + tid] = w3g[tid];
    float dmax = __uint_as_float(*dmaxp);
    if (CACHE) {
        for (int p = tid; p < HW; p += 256)
            dn[p] = __fdiv_rn(dcache[(size_t)b * HW + p], dmax);
    } else {
        float* scr = (float*)lut;   // 2048 floats >= 2*784
        dog_sample(x, b, nbatch, gw, scr, scr + HW, dn, tid);
        for (int p = tid; p < HW; p += 256) dn[p] = __fdiv_rn(dn[p], dmax);
    }
    __syncthreads();

    // ---------------- init phase 1: conv1 LUT + zero t=0 masks ----------------
    for (int e = tid; e < 512; e += 256) {
        float a0 = 0.f, a1 = 0.f, a2 = 0.f, a3 = 0.f;
        #pragma unroll
        for (int k = 0; k < 9; ++k) {
            bool bit = (e >> k) & 1;
            a0 = fadd(a0, bit ? wts[k]      : 0.0f);
            a1 = fadd(a1, bit ? wts[9 + k]  : 0.0f);
            a2 = fadd(a2, bit ? wts[18 + k] : 0.0f);
            a3 = fadd(a3, bit ? wts[27 + k] : 0.0f);
        }
        lut[e] = make_float4(a0, a1, a2, a3);
    }
    if (tid < 28) s1m[0][tid] = 0u;
    else if (tid < 80) p1m[0][tid - 28] = 0u;
    __syncthreads();

    // ---------------- load per-thread constants ----------------
    float dnr[4];
    #pragma unroll
    for (int k = 0; k < 4; ++k) {
        int e = tid + (k << 8);
        dnr[k] = (e < HW) ? dn[e] : 0.f;
    }
    float w2r[36];
    #pragma unroll
    for (int m = 0; m < 36; ++m) w2r[m] = wts[36 + c2 * 36 + m];

    // ---------------- layer1(0) -> s1m[0] ----------------
    #pragma unroll
    for (int k = 0; k < 4; ++k) {
        if (k < 3 || tid < 16) {
            float v = fadd(v1m[k], dnr[k]);
            bool spk = v >= 4.5f;
            v1m[k] = spk ? 0.f : v;
            if (spk) atomicOr(&s1m[0][l1w_[k]], l1b_[k]);
        }
    }
    __syncthreads();

    const float* lutf = (const float*)lut;

    for (int t = 0; t < TSTEPS; ++t) {
        int cur = t & 1, nxt = cur ^ 1;
        // ======== phase B: conv1(t) [all] | conv3(t-1) [240..255] | zeroing ====
        {
            const unsigned* sm = s1m[cur];
            unsigned* pm = p1m[cur];
            #pragma unroll
            for (int k = 0; k < 3; ++k) {
                if (k < 2 || tid < 164) {
                    int sr = srow_[k], sh = sh1_[k];
                    unsigned m0 = sm[sr], m1 = sm[sr + 1], m2 = sm[sr + 2], m3 = sm[sr + 3];
                    unsigned cb = 0;
                    #pragma unroll
                    for (int di = 0; di < 2; ++di) {
                        unsigned ra = di ? m1 : m0, rb = di ? m2 : m1, rc = di ? m3 : m2;
                        #pragma unroll
                        for (int dj = 0; dj < 2; ++dj) {
                            unsigned s = (unsigned)(sh + dj);
                            unsigned pat = ((ra >> s) & 7u) | (((rb >> s) & 7u) << 3)
                                         | (((rc >> s) & 7u) << 6);
                            float a = lutf[(pat << 2) + c1_[k]];
                            float v = fadd(v2q[k][di * 2 + dj], a);
                            bool spk = v >= 4.5f;
                            v2q[k][di * 2 + dj] = spk ? 0.f : v;
                            cb |= (unsigned)spk;
                        }
                    }
                    if (cb) atomicOr(&pm[pw1_[k]], pb1_[k]);
                }
            }
            if (tid >= 164 && tid < 192) s1m[nxt][tid - 164] = 0u;
            if (tid >= 192 && tid < 216) p2m[cur][tid - 192] = 0u;
            if (t > 0 && tid >= 240) {
                int qq = tid - 240, rr = qq >> 2, cc = qq & 3;
                const unsigned* zm = p2m[nxt];   // p2m[(t-1)&1]
                float acc = 0.f;
                #pragma unroll
                for (int ic = 0; ic < 4; ++ic)
                    #pragma unroll
                    for (int ki = 0; ki < 3; ++ki) {
                        unsigned rw = zm[ic * 6 + rr + ki] >> (unsigned)cc;
                        #pragma unroll
                        for (int kj = 0; kj < 3; ++kj)
                            acc = fadd(acc, SELW(rw, kj, wts[180 + ic * 9 + ki * 3 + kj]));
                    }
                v4 = fadd(v4, fmul(fsub(acc, v4), 0.5f));
                if (v4 >= 1.0f) { pred += 1.f; v4 = 0.f; }
            }
        }
        __syncthreads();

        // ======== phase A: conv2(t) | layer1(t+1) [all] | zero p1m[nxt] ========
        {
            const unsigned* pmr = p1m[cur];
            #pragma unroll
            for (int k = 0; k < 2; ++k) {
                if (k == 0 ? cv2a : cv2b) {
                    int pr = prow_[k]; unsigned js = (unsigned)jsh_[k];
                    float acc = 0.f;
                    #pragma unroll
                    for (int ic = 0; ic < 4; ++ic)
                        #pragma unroll
                        for (int ki = 0; ki < 3; ++ki) {
                            unsigned rw = pmr[ic * 13 + pr + ki] >> js;
                            acc = fadd(acc, SELW(rw, 0, w2r[ic * 9 + ki * 3 + 0]));
                            acc = fadd(acc, SELW(rw, 1, w2r[ic * 9 + ki * 3 + 1]));
                            acc = fadd(acc, SELW(rw, 2, w2r[ic * 9 + ki * 3 + 2]));
                        }
                    float v = fadd(v3m[k], acc);
                    bool spk = v >= 1.0f;
                    v3m[k] = spk ? 0.f : v;
                    if (spk) atomicOr(&p2m[cur][p2w_[k]], p2b_[k]);
                }
            }
            if (t < TSTEPS - 1) {
                unsigned* sn = s1m[nxt];
                #pragma unroll
                for (int k = 0; k < 4; ++k) {
                    if (k < 3 || tid < 16) {
                        float v = fadd(v1m[k], dnr[k]);
                        bool spk = v >= 4.5f;
                        v1m[k] = spk ? 0.f : v;
                        if (spk) atomicOr(&sn[l1w_[k]], l1b_[k]);
                    }
                }
            }
            if (tid >= 244) {
                for (int w = tid - 244; w < 52; w += 12) p1m[nxt][w] = 0u;
            }
        }
        __syncthreads();
    }

    // ---------------- epilogue: conv3(29) + output ----------------
    if (tid >= 240) {
        int qq = tid - 240, rr = qq >> 2, cc = qq & 3;
        const unsigned* zm = p2m[(TSTEPS - 1) & 1];
        float acc = 0.f;
        #pragma unroll
        for (int ic = 0; ic < 4; ++ic)
            #pragma unroll
            for (int ki = 0; ki < 3; ++ki) {
                unsigned rw = zm[ic * 6 + rr + ki] >> (unsigned)cc;
                #pragma unroll
                for (int kj = 0; kj < 3; ++kj)
                    acc = fadd(acc, SELW(rw, kj, wts[180 + ic * 9 + ki * 3 + kj]));
            }
        v4 = fadd(v4, fmul(fsub(acc, v4), 0.5f));
        if (v4 >= 1.0f) { pred += 1.f; v4 = 0.f; }
        out[(size_t)b * 16 + qq] = __fdiv_rn(pred, 30.0f);
    }
}

extern "C" void kernel_launch(void* const* d_in, const int* in_sizes, int n_in,
                              void* d_out, int out_size, void* d_ws, size_t ws_size,
                              hipStream_t stream) {
    const float* x  = (const float*)d_in[0];
    const float* w1 = (const float*)d_in[1];
    const float* w2 = (const float*)d_in[2];
    const float* w3 = (const float*)d_in[3];
    float* out = (float*)d_out;
    unsigned int* dmax = (unsigned int*)d_ws;
    float* dcache = (float*)((char*)d_ws + 16);

    int nbatch = in_sizes[0] / HW;
    size_t need = 16 + (size_t)nbatch * HW * sizeof(float);
    bool cache = ws_size >= need;

    // numpy-f32 Gaussian weights: exact f32 steps + correctly-rounded exp
    GaussW gw;
    {
        float fw[7];
        for (int k = 0; k < 7; ++k) {
            float iv = (float)(k - 3);
            float q = iv / 2.0f;
            float e = -0.5f * (q * q);
            fw[k] = (float)exp((double)e);
        }
        float s = 0.0f;
        for (int k = 0; k < 7; ++k) s += fw[k];
        for (int k = 0; k < 7; ++k) gw.w[k] = fw[k] / s;
    }

    hipLaunchKernelGGL(init_kernel, dim3(1), dim3(1), 0, stream, dmax);
    if (cache) {
        hipLaunchKernelGGL(dmax_kernel<true>, dim3(nbatch), dim3(256), 0, stream,
                           x, nbatch, gw, dmax, dcache);
        hipLaunchKernelGGL(sim_kernel<true>, dim3(nbatch), dim3(256), 0, stream,
                           x, nbatch, w1, w2, w3, gw, dmax, dcache, out);
    } else {
        hipLaunchKernelGGL(dmax_kernel<false>, dim3(nbatch), dim3(256), 0, stream,
                           x, nbatch, gw, dmax, dcache);
        hipLaunchKernelGGL(sim_kernel<false>, dim3(nbatch), dim3(256), 0, stream,
                           x, nbatch, w1, w2, w3, gw, dmax, dcache, out);
    }
}